// Round 2
// baseline (1134.648 us; speedup 1.0000x reference)
//
#include <hip/hip_runtime.h>
#include <hip/hip_bf16.h>
#include <math.h>

#define EPSBN 1e-5f

typedef short short8 __attribute__((ext_vector_type(8)));
typedef short short4v __attribute__((ext_vector_type(4)));
typedef float floatx4 __attribute__((ext_vector_type(4)));

__device__ __forceinline__ float gelu_f(float x) {
    return 0.5f * x * (1.0f + erff(x * 0.70710678118654752f));
}

__device__ __forceinline__ unsigned short f2bf(float f) {
    union { float f; unsigned int u; } c; c.f = f;
    unsigned int u = c.u;
    unsigned int r = (u + 0x7FFFu + ((u >> 16) & 1u)) >> 16;   // RNE
    return (unsigned short)r;
}

__device__ __forceinline__ float bf2f(unsigned short h) {
    union { unsigned int u; float f; } c; c.u = ((unsigned int)h) << 16;
    return c.f;
}

// ---------------- weight preps ----------------
// region weights: [G][oc][ic][3][3] fp32 -> [G][oc][t][ic] bf16
__global__ void wprep_bf16_k(const float* __restrict__ w, unsigned short* __restrict__ wb,
                             long total) {
    for (long o = (long)blockIdx.x * blockDim.x + threadIdx.x; o < total;
         o += (long)gridDim.x * blockDim.x) {
        int ic = (int)(o % 192); long t0 = o / 192;
        int t = (int)(t0 % 9); long t1 = t0 / 9;
        int oc = (int)(t1 % 192); long g = t1 / 192;
        wb[o] = f2bf(w[(((size_t)g * 192 + oc) * 192 + ic) * 9 + t]);
    }
}

// downsample weights: [OC][192][2][2] fp32 -> [t4][OC][192] bf16
__global__ void wprep_tap_k(const float* __restrict__ w, unsigned short* __restrict__ wb,
                            int OC) {
    long total = (long)4 * OC * 192;
    for (long o = (long)blockIdx.x * blockDim.x + threadIdx.x; o < total;
         o += (long)gridDim.x * blockDim.x) {
        int ic = (int)(o % 192); long t0 = o / 192;
        int oc = (int)(t0 % OC); int t = (int)(t0 / OC);
        wb[o] = f2bf(w[((size_t)oc * 192 + ic) * 4 + t]);
    }
}

// conv1 weights: [192][48] -> [48][192] fp32
__global__ void wprep_wt1_k(const float* __restrict__ w, float* __restrict__ wt) {
    int o = blockIdx.x * 256 + threadIdx.x;
    if (o < 9216) {
        int oc = o % 192, k = o / 192;
        wt[o] = w[oc * 48 + k];
    }
}

// ---------------- conv1: 3->192, 4x4 stride 4, BN+GELU, NHWC bf16 out ----------------
__global__ __launch_bounds__(192) void conv1_k(
        const float* __restrict__ x, const float* __restrict__ wt1,
        const float* __restrict__ bg, const float* __restrict__ bb,
        const float* __restrict__ bm, const float* __restrict__ bv,
        unsigned short* __restrict__ h1c) {
    __shared__ float xs[3][4][224];
    int b = blockIdx.x / 56, oy = blockIdx.x % 56;
    int tid = threadIdx.x;
    for (int i = tid; i < 2688; i += 192) {
        int col = i % 224, r = (i / 224) % 4, c = i / 896;
        xs[c][r][col] = x[(((size_t)b * 3 + c) * 224 + 4 * oy + r) * 224 + col];
    }
    float w[48];
    #pragma unroll
    for (int k = 0; k < 48; k++) w[k] = wt1[k * 192 + tid];
    float inv = bg[tid] * rsqrtf(bv[tid] + EPSBN);
    float bet = bb[tid] - bm[tid] * inv;
    __syncthreads();
    for (int ox = 0; ox < 56; ox++) {
        float a = 0.f;
        #pragma unroll
        for (int c = 0; c < 3; c++) {
            #pragma unroll
            for (int ky = 0; ky < 4; ky++) {
                float4 v = *(const float4*)&xs[c][ky][4 * ox];
                const float* wk = &w[(c * 4 + ky) * 4];
                a += v.x * wk[0] + v.y * wk[1] + v.z * wk[2] + v.w * wk[3];
            }
        }
        h1c[(((size_t)b * 56 + oy) * 56 + ox) * 192 + tid] = f2bf(gelu_f(a * inv + bet));
    }
}

// ---------------- region conv via MFMA v4: wave = 1 tile x 64px x 96oc ----------------
// block = (g, batch-pair): 4 waves = {tile 0,1} x {oc-half 0,1}. Each wave: M=4 m-frags
// (49 px of its tile), N=6 n-frags (96 oc). LDS A-reads per 24 MFMAs drop 8 -> 4
// (per-SIMD LDS demand 281 -> 141 B/cyc: was the MfmaUtil=29% wall). Weight slab is
// read 2x per block from L2 (~18 TB/s aggregate, under the 34.5 TB/s ceiling).
// Residual re-read from global (L2-hot). XCD swizzle keeps slab L2-resident.
#define RST 200
#define TILE_SH (81 * RST)
template<int INF32>
__global__ __launch_bounds__(256, 2) void region_mfma3_k(
        const void* __restrict__ inbuf, void* __restrict__ outbuf,
        const unsigned short* __restrict__ wb,
        const float* __restrict__ pg, const float* __restrict__ pb,
        const float* __restrict__ pm, const float* __restrict__ pv,
        int gw, int W) {
    __shared__ unsigned short lds[2 * TILE_SH];   // 64,800 B -> 2 blocks/CU
    const int raw = blockIdx.x;
    const int g = (raw & 7) + 8 * (raw >> 8);
    const int bp = (raw >> 3) & 31;
    const int b0 = bp * 2;
    const int gy = g / gw, gx = g % gw;
    const int Y0 = gy * 7, X0 = gx * 7;
    const int tid = threadIdx.x;
    const int lane = tid & 63;
    const int wid = tid >> 6;
    const int tIw = wid & 1;        // this wave's tile
    const int och = wid >> 1;       // this wave's oc half (0: oc 0-95, 1: oc 96-191)
    const int quad = lane >> 4;
    const int l15 = lane & 15;

    const size_t tsz = (size_t)W * W * 192;
    const size_t slab0 = (size_t)b0 * tsz;

    // halo zero (perimeter cells), vectorized
    for (int i = tid; i < 1536; i += 256) {
        int tI = i / 768, rem = i % 768, h = rem / 24, ch = rem % 24;
        int cell;
        if (h < 9) cell = h;
        else if (h < 18) cell = 72 + (h - 9);
        else { int h2 = h - 18; cell = (1 + (h2 >> 1)) * 9 + ((h2 & 1) * 8); }
        *(short8*)&lds[tI * TILE_SH + cell * RST + ch * 8] = (short8)0;
    }
    // interior fill, b128 per lane
    for (int i = tid; i < 2352; i += 256) {
        int tI = i / 1176, rem = i % 1176, p = rem / 24, ch = rem % 24;
        int y = p / 7, xx = p % 7;
        size_t poff = slab0 + (size_t)tI * tsz + ((size_t)(Y0 + y) * W + (X0 + xx)) * 192 + ch * 8;
        short8 v;
        if (INF32) {
            const float* s4 = (const float*)inbuf + poff;
            float4 a = *(const float4*)s4;
            float4 b2 = *(const float4*)(s4 + 4);
            v[0] = (short)f2bf(a.x);  v[1] = (short)f2bf(a.y);
            v[2] = (short)f2bf(a.z);  v[3] = (short)f2bf(a.w);
            v[4] = (short)f2bf(b2.x); v[5] = (short)f2bf(b2.y);
            v[6] = (short)f2bf(b2.z); v[7] = (short)f2bf(b2.w);
        } else {
            v = *(const short8*)((const unsigned short*)inbuf + poff);
        }
        *(short8*)&lds[tI * TILE_SH + ((y + 1) * 9 + (xx + 1)) * RST + ch * 8] = v;
    }
    __syncthreads();

    // per-lane m-frag pixel coords (this wave's tile only)
    int pyv[4], pxv[4];
    #pragma unroll
    for (int f = 0; f < 4; f++) {
        int p = f * 16 + l15; if (p > 48) p = 48;
        pyv[f] = p / 7; pxv[f] = p % 7;
    }
    // weight offsets: oc = och*96 + nt*16 + l15, nt = 0..5
    int woff[6];
    #pragma unroll
    for (int nt = 0; nt < 6; nt++)
        woff[nt] = (och * 96 + nt * 16 + l15) * 1728 + quad * 8;
    const unsigned short* wbg = wb + (size_t)g * 331776;

    floatx4 acc[4][6];
    #pragma unroll
    for (int m = 0; m < 4; m++)
        #pragma unroll
        for (int nt = 0; nt < 6; nt++) acc[m][nt] = (floatx4)0.f;

    const int tbase = tIw * TILE_SH;
    for (int t = 0; t < 9; t++) {
        const int ky = t / 3, kx = t % 3;
        int ca[4];
        #pragma unroll
        for (int f = 0; f < 4; f++)
            ca[f] = tbase + ((pyv[f] + ky) * 9 + (pxv[f] + kx)) * RST + quad * 8;
        const int toff = t * 192;
        #pragma unroll
        for (int s = 0; s < 6; s++) {
            const int ic0 = s * 32;
            short8 wf[6];
            #pragma unroll
            for (int nt = 0; nt < 6; nt++)
                wf[nt] = *(const short8*)(wbg + woff[nt] + toff + ic0);
            short8 pf[4];
            #pragma unroll
            for (int m = 0; m < 4; m++)
                pf[m] = *(const short8*)&lds[ca[m] + ic0];
            #pragma unroll
            for (int m = 0; m < 4; m++)
                #pragma unroll
                for (int nt = 0; nt < 6; nt++)
                    acc[m][nt] = __builtin_amdgcn_mfma_f32_16x16x32_bf16(pf[m], wf[nt], acc[m][nt], 0, 0, 0);
        }
    }

    // epilogue: C row = pixel (m*16 + quad*4 + r), col = oc (l15). Residual from global.
    const size_t tslab = slab0 + (size_t)tIw * tsz;
    unsigned short* outb = (unsigned short*)outbuf + tslab;
    const float* resf = (const float*)inbuf + tslab;
    const unsigned short* resu = (const unsigned short*)inbuf + tslab;
    #pragma unroll
    for (int nt = 0; nt < 6; nt++) {
        int oc = och * 96 + nt * 16 + l15;
        float inv = pg[g * 192 + oc] * rsqrtf(pv[g * 192 + oc] + EPSBN);
        float bet = pb[g * 192 + oc] - pm[g * 192 + oc] * inv;
        #pragma unroll
        for (int m = 0; m < 4; m++) {
            #pragma unroll
            for (int r = 0; r < 4; r++) {
                int p = m * 16 + quad * 4 + r;
                if (p < 49) {
                    int y = p / 7, xx = p % 7;
                    size_t pix = (size_t)(Y0 + y) * W + (X0 + xx);
                    float res = INF32 ? resf[pix * 192 + oc] : bf2f(resu[pix * 192 + oc]);
                    outb[pix * 192 + oc] = f2bf(gelu_f(acc[m][nt][r] * inv + bet) + res);
                }
            }
        }
    }
}

// ---------------- conv2 via MFMA: 192->192, 2x2 s2, BN+GELU, bf16NHWC -> fp32NHWC ----------
__global__ __launch_bounds__(256) void conv2_mfma_k(
        const unsigned short* __restrict__ h1c, const unsigned short* __restrict__ wb,
        const float* __restrict__ bg, const float* __restrict__ bb,
        const float* __restrict__ bm, const float* __restrict__ bv,
        float* __restrict__ h2c) {
    __shared__ unsigned short lds[2 * 112 * 40];
    const int b = blockIdx.x / 7;
    const int oy0 = (blockIdx.x % 7) * 4;
    const int tid = threadIdx.x;
    const int lane = tid & 63;
    const int wid = tid >> 6;
    const int quad = lane >> 4;
    const int l15 = lane & 15;

    floatx4 acc[7][3];
    #pragma unroll
    for (int mt = 0; mt < 7; mt++)
        #pragma unroll
        for (int nt = 0; nt < 3; nt++) acc[mt][nt] = (floatx4)0.f;

    for (int ky = 0; ky < 2; ky++) {
        for (int c = 0; c < 6; c++) {
            __syncthreads();
            for (int i = tid; i < 1792; i += 256) {
                int icq = i & 7, kx = (i >> 3) & 1, p = i >> 4;
                int oy = oy0 + p / 28, ox = p % 28;
                int iy = 2 * oy + ky, ix = 2 * ox + kx;
                const unsigned short* src =
                    h1c + (((size_t)b * 56 + iy) * 56 + ix) * 192 + c * 32 + icq * 4;
                *(short4v*)(&lds[kx * 4480 + p * 40 + icq * 4]) = *(const short4v*)src;
            }
            __syncthreads();
            #pragma unroll
            for (int kx = 0; kx < 2; kx++) {
                const int t = ky * 2 + kx;
                short8 wf[3];
                #pragma unroll
                for (int nt = 0; nt < 3; nt++) {
                    int oc = wid * 48 + nt * 16 + l15;
                    wf[nt] = *(const short8*)(wb + ((size_t)(t * 192 + oc)) * 192 + c * 32 + quad * 8);
                }
                #pragma unroll
                for (int mt = 0; mt < 7; mt++) {
                    short8 ap = *(const short8*)(&lds[kx * 4480 + (mt * 16 + l15) * 40 + quad * 8]);
                    #pragma unroll
                    for (int nt = 0; nt < 3; nt++)
                        acc[mt][nt] = __builtin_amdgcn_mfma_f32_16x16x32_bf16(ap, wf[nt], acc[mt][nt], 0, 0, 0);
                }
            }
        }
    }
    #pragma unroll
    for (int nt = 0; nt < 3; nt++) {
        int oc = wid * 48 + nt * 16 + l15;
        float inv = bg[oc] * rsqrtf(bv[oc] + EPSBN);
        float bet = bb[oc] - bm[oc] * inv;
        #pragma unroll
        for (int mt = 0; mt < 7; mt++) {
            #pragma unroll
            for (int r = 0; r < 4; r++) {
                int p = mt * 16 + quad * 4 + r;
                int oy = oy0 + p / 28, ox = p % 28;
                h2c[(((size_t)b * 28 + oy) * 28 + ox) * 192 + oc] = gelu_f(acc[mt][nt][r] * inv + bet);
            }
        }
    }
}

// ---------------- conv3 via MFMA: 192->768, 2x2 s2, BN, bf16NHWC -> out (B,196,768) ----
__global__ __launch_bounds__(256) void conv3_mfma_k(
        const unsigned short* __restrict__ h2b, const unsigned short* __restrict__ wb,
        const float* __restrict__ bg, const float* __restrict__ bb,
        const float* __restrict__ bm, const float* __restrict__ bv,
        float* __restrict__ out) {
    __shared__ unsigned short lds[2 * 112 * 40];
    const int bid = blockIdx.x;
    const int b = bid / 6;
    const int s = (bid % 6) / 3;
    const int octile = bid % 3;
    const int y0 = s * 7;
    const int tid = threadIdx.x;
    const int lane = tid & 63;
    const int wid = tid >> 6;
    const int quad = lane >> 4;
    const int l15 = lane & 15;

    floatx4 acc[7][4];
    #pragma unroll
    for (int mt = 0; mt < 7; mt++)
        #pragma unroll
        for (int nt = 0; nt < 4; nt++) acc[mt][nt] = (floatx4)0.f;

    for (int ky = 0; ky < 2; ky++) {
        for (int c = 0; c < 6; c++) {
            __syncthreads();
            for (int i = tid; i < 1568; i += 256) {
                int icq = i & 7, kx = (i >> 3) & 1, p = i >> 4;
                int oy = y0 + p / 14, ox = p % 14;
                int iy = 2 * oy + ky, ix = 2 * ox + kx;
                const unsigned short* src =
                    h2b + (((size_t)b * 28 + iy) * 28 + ix) * 192 + c * 32 + icq * 4;
                *(short4v*)(&lds[kx * 4480 + p * 40 + icq * 4]) = *(const short4v*)src;
            }
            __syncthreads();
            #pragma unroll
            for (int kx = 0; kx < 2; kx++) {
                const int t = ky * 2 + kx;
                short8 wf[4];
                #pragma unroll
                for (int nt = 0; nt < 4; nt++) {
                    int oc = octile * 256 + wid * 64 + nt * 16 + l15;
                    wf[nt] = *(const short8*)(wb + ((size_t)(t * 768 + oc)) * 192 + c * 32 + quad * 8);
                }
                #pragma unroll
                for (int mt = 0; mt < 7; mt++) {
                    int p = mt * 16 + l15; if (p > 97) p = 97;
                    short8 ap = *(const short8*)(&lds[kx * 4480 + p * 40 + quad * 8]);
                    #pragma unroll
                    for (int nt = 0; nt < 4; nt++)
                        acc[mt][nt] = __builtin_amdgcn_mfma_f32_16x16x32_bf16(ap, wf[nt], acc[mt][nt], 0, 0, 0);
                }
            }
        }
    }
    #pragma unroll
    for (int nt = 0; nt < 4; nt++) {
        int oc = octile * 256 + wid * 64 + nt * 16 + l15;
        float inv = bg[oc] * rsqrtf(bv[oc] + EPSBN);
        float bet = bb[oc] - bm[oc] * inv;
        #pragma unroll
        for (int mt = 0; mt < 7; mt++) {
            #pragma unroll
            for (int r = 0; r < 4; r++) {
                int p = mt * 16 + quad * 4 + r;
                if (p < 98) {
                    int oy = y0 + p / 14, ox = p % 14;
                    out[((size_t)b * 196 + oy * 14 + ox) * 768 + oc] = acc[mt][nt][r] * inv + bet;
                }
            }
        }
    }
}

extern "C" void kernel_launch(void* const* d_in, const int* in_sizes, int n_in,
                              void* d_out, int out_size, void* d_ws, size_t ws_size,
                              hipStream_t stream) {
    const float* x   = (const float*)d_in[0];
    const float* w1  = (const float*)d_in[1];
    const float* b1g = (const float*)d_in[2];
    const float* b1b = (const float*)d_in[3];
    const float* b1m = (const float*)d_in[4];
    const float* b1v = (const float*)d_in[5];
    const float* r1w = (const float*)d_in[6];
    const float* r1g = (const float*)d_in[7];
    const float* r1b = (const float*)d_in[8];
    const float* r1m = (const float*)d_in[9];
    const float* r1v = (const float*)d_in[10];
    const float* w2  = (const float*)d_in[11];
    const float* b2g = (const float*)d_in[12];
    const float* b2b = (const float*)d_in[13];
    const float* b2m = (const float*)d_in[14];
    const float* b2v = (const float*)d_in[15];
    const float* r2w = (const float*)d_in[16];
    const float* r2g = (const float*)d_in[17];
    const float* r2b = (const float*)d_in[18];
    const float* r2m = (const float*)d_in[19];
    const float* r2v = (const float*)d_in[20];
    const float* w3  = (const float*)d_in[21];
    const float* b3g = (const float*)d_in[22];
    const float* b3b = (const float*)d_in[23];
    const float* b3m = (const float*)d_in[24];
    const float* b3v = (const float*)d_in[25];
    float* out = (float*)d_out;

    char* ws = (char*)d_ws;
    unsigned short* h1c  = (unsigned short*)(ws + 0);            // 77,070,336  bf16 NHWC 56x56
    float*          h2c  = (float*)         (ws + 77070336UL);   // 38,535,168  fp32 NHWC 28x28
    unsigned short* h2b  = (unsigned short*)(ws + 115605504UL);  // 19,267,584  bf16 NHWC 28x28
    unsigned short* wb1  = (unsigned short*)(ws + 134873088UL);  // 42,467,328
    unsigned short* wb2r = (unsigned short*)(ws + 177340416UL);  // 10,616,832
    float*          wt1  = (float*)         (ws + 187957248UL);  //     36,864
    unsigned short* wb2c = (unsigned short*)(ws + 187994112UL);  //    294,912
    unsigned short* wb3c = (unsigned short*)(ws + 188289024UL);  //  1,179,648
    // total 189,468,672 B

    wprep_bf16_k<<<8192, 256, 0, stream>>>(r1w, wb1, (long)64 * 192 * 9 * 192);
    wprep_bf16_k<<<2048, 256, 0, stream>>>(r2w, wb2r, (long)16 * 192 * 9 * 192);
    wprep_tap_k<<<576, 256, 0, stream>>>(w2, wb2c, 192);
    wprep_tap_k<<<2304, 256, 0, stream>>>(w3, wb3c, 768);
    wprep_wt1_k<<<36, 256, 0, stream>>>(w1, wt1);

    conv1_k<<<64 * 56, 192, 0, stream>>>(x, wt1, b1g, b1b, b1m, b1v, h1c);
    region_mfma3_k<0><<<64 * 32, 256, 0, stream>>>(h1c, h1c, wb1, r1g, r1b, r1m, r1v, 8, 56);
    conv2_mfma_k<<<64 * 7, 256, 0, stream>>>(h1c, wb2c, b2g, b2b, b2m, b2v, h2c);
    region_mfma3_k<1><<<16 * 32, 256, 0, stream>>>(h2c, h2b, wb2r, r2g, r2b, r2m, r2v, 4, 28);
    conv3_mfma_k<<<64 * 6, 256, 0, stream>>>(h2b, wb3c, b3g, b3b, b3m, b3v, out);
}

// Round 3
// 994.253 us; speedup vs baseline: 1.1412x; 1.1412x over previous
//
#include <hip/hip_runtime.h>
#include <hip/hip_bf16.h>
#include <math.h>

#define EPSBN 1e-5f

typedef short short8 __attribute__((ext_vector_type(8)));
typedef short short4v __attribute__((ext_vector_type(4)));
typedef float floatx4 __attribute__((ext_vector_type(4)));

__device__ __forceinline__ float gelu_f(float x) {
    return 0.5f * x * (1.0f + erff(x * 0.70710678118654752f));
}

__device__ __forceinline__ unsigned short f2bf(float f) {
    union { float f; unsigned int u; } c; c.f = f;
    unsigned int u = c.u;
    unsigned int r = (u + 0x7FFFu + ((u >> 16) & 1u)) >> 16;   // RNE
    return (unsigned short)r;
}

__device__ __forceinline__ float bf2f(unsigned short h) {
    union { unsigned int u; float f; } c; c.u = ((unsigned int)h) << 16;
    return c.f;
}

// ---------------- weight preps ----------------
// region weights: [G][oc][ic][3][3] fp32 -> [G][oc][t][ic] bf16
__global__ void wprep_bf16_k(const float* __restrict__ w, unsigned short* __restrict__ wb,
                             long total) {
    for (long o = (long)blockIdx.x * blockDim.x + threadIdx.x; o < total;
         o += (long)gridDim.x * blockDim.x) {
        int ic = (int)(o % 192); long t0 = o / 192;
        int t = (int)(t0 % 9); long t1 = t0 / 9;
        int oc = (int)(t1 % 192); long g = t1 / 192;
        wb[o] = f2bf(w[(((size_t)g * 192 + oc) * 192 + ic) * 9 + t]);
    }
}

// downsample weights: [OC][192][2][2] fp32 -> [t4][OC][192] bf16
__global__ void wprep_tap_k(const float* __restrict__ w, unsigned short* __restrict__ wb,
                            int OC) {
    long total = (long)4 * OC * 192;
    for (long o = (long)blockIdx.x * blockDim.x + threadIdx.x; o < total;
         o += (long)gridDim.x * blockDim.x) {
        int ic = (int)(o % 192); long t0 = o / 192;
        int oc = (int)(t0 % OC); int t = (int)(t0 / OC);
        wb[o] = f2bf(w[((size_t)oc * 192 + ic) * 4 + t]);
    }
}

// conv1 weights: [192][48] -> [48][192] fp32
__global__ void wprep_wt1_k(const float* __restrict__ w, float* __restrict__ wt) {
    int o = blockIdx.x * 256 + threadIdx.x;
    if (o < 9216) {
        int oc = o % 192, k = o / 192;
        wt[o] = w[oc * 48 + k];
    }
}

// ---------------- conv1: 3->192, 4x4 stride 4, BN+GELU, NHWC bf16 out ----------------
__global__ __launch_bounds__(192) void conv1_k(
        const float* __restrict__ x, const float* __restrict__ wt1,
        const float* __restrict__ bg, const float* __restrict__ bb,
        const float* __restrict__ bm, const float* __restrict__ bv,
        unsigned short* __restrict__ h1c) {
    __shared__ float xs[3][4][224];
    int b = blockIdx.x / 56, oy = blockIdx.x % 56;
    int tid = threadIdx.x;
    for (int i = tid; i < 2688; i += 192) {
        int col = i % 224, r = (i / 224) % 4, c = i / 896;
        xs[c][r][col] = x[(((size_t)b * 3 + c) * 224 + 4 * oy + r) * 224 + col];
    }
    float w[48];
    #pragma unroll
    for (int k = 0; k < 48; k++) w[k] = wt1[k * 192 + tid];
    float inv = bg[tid] * rsqrtf(bv[tid] + EPSBN);
    float bet = bb[tid] - bm[tid] * inv;
    __syncthreads();
    for (int ox = 0; ox < 56; ox++) {
        float a = 0.f;
        #pragma unroll
        for (int c = 0; c < 3; c++) {
            #pragma unroll
            for (int ky = 0; ky < 4; ky++) {
                float4 v = *(const float4*)&xs[c][ky][4 * ox];
                const float* wk = &w[(c * 4 + ky) * 4];
                a += v.x * wk[0] + v.y * wk[1] + v.z * wk[2] + v.w * wk[3];
            }
        }
        h1c[(((size_t)b * 56 + oy) * 56 + ox) * 192 + tid] = f2bf(gelu_f(a * inv + bet));
    }
}

// ---------------- region conv via MFMA v5: 1-tile blocks, 4 blocks/CU ----------------
// Post-mortem R2: both partitions sit under every throughput roof (LDS 0.0208 vs 0.0252
// B/FLOP budget; L2 0.0078 vs 0.0166) yet idle ~70% -> LATENCY-bound at 8 waves/CU.
// v5: block = (g, single batch) = 1 tile (32.4KB LDS) -> 4 blocks/CU = 16 waves/CU.
// Wave partition back to proven M4xN3 (48 oc/wave, 3 global + 4 LDS loads per step).
// Swizzle keeps same-g blocks co-resident per XCD so the 2x nominal weight re-read
// dedups in L1/L2. __launch_bounds__(256,4) caps regs at 128 for 4 waves/SIMD.
#define RST 200
#define TILE_SH (81 * RST)
template<int INF32>
__global__ __launch_bounds__(256, 4) void region_mfma4_k(
        const void* __restrict__ inbuf, void* __restrict__ outbuf,
        const unsigned short* __restrict__ wb,
        const float* __restrict__ pg, const float* __restrict__ pb,
        const float* __restrict__ pm, const float* __restrict__ pv,
        int gw, int W) {
    __shared__ unsigned short lds[TILE_SH];   // 32,400 B -> 4 blocks/CU
    const int raw = blockIdx.x;
    const int xcd = raw & 7;
    const int ii = raw >> 3;
    const int g = xcd + 8 * (ii >> 6);        // same-g blocks adjacent on same XCD
    const int b = ii & 63;
    const int gy = g / gw, gx = g % gw;
    const int Y0 = gy * 7, X0 = gx * 7;
    const int tid = threadIdx.x;
    const int lane = tid & 63;
    const int wid = tid >> 6;
    const int quad = lane >> 4;
    const int l15 = lane & 15;

    const size_t tsz = (size_t)W * W * 192;
    const size_t tslab = (size_t)b * tsz;

    // halo zero (perimeter cells), vectorized: 32 cells x 24 ch-groups
    for (int i = tid; i < 768; i += 256) {
        int h = i / 24, ch = i % 24;
        int cell;
        if (h < 9) cell = h;
        else if (h < 18) cell = 72 + (h - 9);
        else { int h2 = h - 18; cell = (1 + (h2 >> 1)) * 9 + ((h2 & 1) * 8); }
        *(short8*)&lds[cell * RST + ch * 8] = (short8)0;
    }
    // interior fill, b128 per lane: 49 px x 24 ch-groups
    for (int i = tid; i < 1176; i += 256) {
        int p = i / 24, ch = i % 24;
        int y = p / 7, xx = p % 7;
        size_t poff = tslab + ((size_t)(Y0 + y) * W + (X0 + xx)) * 192 + ch * 8;
        short8 v;
        if (INF32) {
            const float* s4 = (const float*)inbuf + poff;
            float4 a = *(const float4*)s4;
            float4 b2 = *(const float4*)(s4 + 4);
            v[0] = (short)f2bf(a.x);  v[1] = (short)f2bf(a.y);
            v[2] = (short)f2bf(a.z);  v[3] = (short)f2bf(a.w);
            v[4] = (short)f2bf(b2.x); v[5] = (short)f2bf(b2.y);
            v[6] = (short)f2bf(b2.z); v[7] = (short)f2bf(b2.w);
        } else {
            v = *(const short8*)((const unsigned short*)inbuf + poff);
        }
        *(short8*)&lds[((y + 1) * 9 + (xx + 1)) * RST + ch * 8] = v;
    }
    __syncthreads();

    // per-lane m-frag pixel coords
    int pyv[4], pxv[4];
    #pragma unroll
    for (int f = 0; f < 4; f++) {
        int p = f * 16 + l15; if (p > 48) p = 48;
        pyv[f] = p / 7; pxv[f] = p % 7;
    }
    // weight offsets: oc = wid*48 + nt*16 + l15
    int woff[3];
    #pragma unroll
    for (int nt = 0; nt < 3; nt++)
        woff[nt] = (wid * 48 + nt * 16 + l15) * 1728 + quad * 8;
    const unsigned short* wbg = wb + (size_t)g * 331776;

    floatx4 acc[4][3];
    #pragma unroll
    for (int m = 0; m < 4; m++)
        #pragma unroll
        for (int nt = 0; nt < 3; nt++) acc[m][nt] = (floatx4)0.f;

    for (int t = 0; t < 9; t++) {
        const int ky = t / 3, kx = t % 3;
        int ca[4];
        #pragma unroll
        for (int f = 0; f < 4; f++)
            ca[f] = ((pyv[f] + ky) * 9 + (pxv[f] + kx)) * RST + quad * 8;
        const int toff = t * 192;
        #pragma unroll
        for (int s = 0; s < 6; s++) {
            const int ic0 = s * 32;
            short8 wf[3];
            #pragma unroll
            for (int nt = 0; nt < 3; nt++)
                wf[nt] = *(const short8*)(wbg + woff[nt] + toff + ic0);
            short8 pf[4];
            #pragma unroll
            for (int m = 0; m < 4; m++)
                pf[m] = *(const short8*)&lds[ca[m] + ic0];
            #pragma unroll
            for (int m = 0; m < 4; m++)
                #pragma unroll
                for (int nt = 0; nt < 3; nt++)
                    acc[m][nt] = __builtin_amdgcn_mfma_f32_16x16x32_bf16(pf[m], wf[nt], acc[m][nt], 0, 0, 0);
        }
    }

    // epilogue: C row = pixel (m*16 + quad*4 + r), col = oc (l15). Residual from global.
    unsigned short* outb = (unsigned short*)outbuf + tslab;
    const float* resf = (const float*)inbuf + tslab;
    const unsigned short* resu = (const unsigned short*)inbuf + tslab;
    #pragma unroll
    for (int nt = 0; nt < 3; nt++) {
        int oc = wid * 48 + nt * 16 + l15;
        float inv = pg[g * 192 + oc] * rsqrtf(pv[g * 192 + oc] + EPSBN);
        float bet = pb[g * 192 + oc] - pm[g * 192 + oc] * inv;
        #pragma unroll
        for (int m = 0; m < 4; m++) {
            #pragma unroll
            for (int r = 0; r < 4; r++) {
                int p = m * 16 + quad * 4 + r;
                if (p < 49) {
                    int y = p / 7, xx = p % 7;
                    size_t pix = (size_t)(Y0 + y) * W + (X0 + xx);
                    float res = INF32 ? resf[pix * 192 + oc] : bf2f(resu[pix * 192 + oc]);
                    outb[pix * 192 + oc] = f2bf(gelu_f(acc[m][nt][r] * inv + bet) + res);
                }
            }
        }
    }
}

// ---------------- conv2 via MFMA: 192->192, 2x2 s2, BN+GELU, bf16NHWC -> fp32NHWC ----------
__global__ __launch_bounds__(256) void conv2_mfma_k(
        const unsigned short* __restrict__ h1c, const unsigned short* __restrict__ wb,
        const float* __restrict__ bg, const float* __restrict__ bb,
        const float* __restrict__ bm, const float* __restrict__ bv,
        float* __restrict__ h2c) {
    __shared__ unsigned short lds[2 * 112 * 40];
    const int b = blockIdx.x / 7;
    const int oy0 = (blockIdx.x % 7) * 4;
    const int tid = threadIdx.x;
    const int lane = tid & 63;
    const int wid = tid >> 6;
    const int quad = lane >> 4;
    const int l15 = lane & 15;

    floatx4 acc[7][3];
    #pragma unroll
    for (int mt = 0; mt < 7; mt++)
        #pragma unroll
        for (int nt = 0; nt < 3; nt++) acc[mt][nt] = (floatx4)0.f;

    for (int ky = 0; ky < 2; ky++) {
        for (int c = 0; c < 6; c++) {
            __syncthreads();
            for (int i = tid; i < 1792; i += 256) {
                int icq = i & 7, kx = (i >> 3) & 1, p = i >> 4;
                int oy = oy0 + p / 28, ox = p % 28;
                int iy = 2 * oy + ky, ix = 2 * ox + kx;
                const unsigned short* src =
                    h1c + (((size_t)b * 56 + iy) * 56 + ix) * 192 + c * 32 + icq * 4;
                *(short4v*)(&lds[kx * 4480 + p * 40 + icq * 4]) = *(const short4v*)src;
            }
            __syncthreads();
            #pragma unroll
            for (int kx = 0; kx < 2; kx++) {
                const int t = ky * 2 + kx;
                short8 wf[3];
                #pragma unroll
                for (int nt = 0; nt < 3; nt++) {
                    int oc = wid * 48 + nt * 16 + l15;
                    wf[nt] = *(const short8*)(wb + ((size_t)(t * 192 + oc)) * 192 + c * 32 + quad * 8);
                }
                #pragma unroll
                for (int mt = 0; mt < 7; mt++) {
                    short8 ap = *(const short8*)(&lds[kx * 4480 + (mt * 16 + l15) * 40 + quad * 8]);
                    #pragma unroll
                    for (int nt = 0; nt < 3; nt++)
                        acc[mt][nt] = __builtin_amdgcn_mfma_f32_16x16x32_bf16(ap, wf[nt], acc[mt][nt], 0, 0, 0);
                }
            }
        }
    }
    #pragma unroll
    for (int nt = 0; nt < 3; nt++) {
        int oc = wid * 48 + nt * 16 + l15;
        float inv = bg[oc] * rsqrtf(bv[oc] + EPSBN);
        float bet = bb[oc] - bm[oc] * inv;
        #pragma unroll
        for (int mt = 0; mt < 7; mt++) {
            #pragma unroll
            for (int r = 0; r < 4; r++) {
                int p = mt * 16 + quad * 4 + r;
                int oy = oy0 + p / 28, ox = p % 28;
                h2c[(((size_t)b * 28 + oy) * 28 + ox) * 192 + oc] = gelu_f(acc[mt][nt][r] * inv + bet);
            }
        }
    }
}

// ---------------- conv3 via MFMA: 192->768, 2x2 s2, BN, bf16NHWC -> out (B,196,768) ----
__global__ __launch_bounds__(256) void conv3_mfma_k(
        const unsigned short* __restrict__ h2b, const unsigned short* __restrict__ wb,
        const float* __restrict__ bg, const float* __restrict__ bb,
        const float* __restrict__ bm, const float* __restrict__ bv,
        float* __restrict__ out) {
    __shared__ unsigned short lds[2 * 112 * 40];
    const int bid = blockIdx.x;
    const int b = bid / 6;
    const int s = (bid % 6) / 3;
    const int octile = bid % 3;
    const int y0 = s * 7;
    const int tid = threadIdx.x;
    const int lane = tid & 63;
    const int wid = tid >> 6;
    const int quad = lane >> 4;
    const int l15 = lane & 15;

    floatx4 acc[7][4];
    #pragma unroll
    for (int mt = 0; mt < 7; mt++)
        #pragma unroll
        for (int nt = 0; nt < 4; nt++) acc[mt][nt] = (floatx4)0.f;

    for (int ky = 0; ky < 2; ky++) {
        for (int c = 0; c < 6; c++) {
            __syncthreads();
            for (int i = tid; i < 1568; i += 256) {
                int icq = i & 7, kx = (i >> 3) & 1, p = i >> 4;
                int oy = y0 + p / 14, ox = p % 14;
                int iy = 2 * oy + ky, ix = 2 * ox + kx;
                const unsigned short* src =
                    h2b + (((size_t)b * 28 + iy) * 28 + ix) * 192 + c * 32 + icq * 4;
                *(short4v*)(&lds[kx * 4480 + p * 40 + icq * 4]) = *(const short4v*)src;
            }
            __syncthreads();
            #pragma unroll
            for (int kx = 0; kx < 2; kx++) {
                const int t = ky * 2 + kx;
                short8 wf[4];
                #pragma unroll
                for (int nt = 0; nt < 4; nt++) {
                    int oc = octile * 256 + wid * 64 + nt * 16 + l15;
                    wf[nt] = *(const short8*)(wb + ((size_t)(t * 768 + oc)) * 192 + c * 32 + quad * 8);
                }
                #pragma unroll
                for (int mt = 0; mt < 7; mt++) {
                    int p = mt * 16 + l15; if (p > 97) p = 97;
                    short8 ap = *(const short8*)(&lds[kx * 4480 + p * 40 + quad * 8]);
                    #pragma unroll
                    for (int nt = 0; nt < 4; nt++)
                        acc[mt][nt] = __builtin_amdgcn_mfma_f32_16x16x32_bf16(ap, wf[nt], acc[mt][nt], 0, 0, 0);
                }
            }
        }
    }
    #pragma unroll
    for (int nt = 0; nt < 4; nt++) {
        int oc = octile * 256 + wid * 64 + nt * 16 + l15;
        float inv = bg[oc] * rsqrtf(bv[oc] + EPSBN);
        float bet = bb[oc] - bm[oc] * inv;
        #pragma unroll
        for (int mt = 0; mt < 7; mt++) {
            #pragma unroll
            for (int r = 0; r < 4; r++) {
                int p = mt * 16 + quad * 4 + r;
                if (p < 98) {
                    int oy = y0 + p / 14, ox = p % 14;
                    out[((size_t)b * 196 + oy * 14 + ox) * 768 + oc] = acc[mt][nt][r] * inv + bet;
                }
            }
        }
    }
}

extern "C" void kernel_launch(void* const* d_in, const int* in_sizes, int n_in,
                              void* d_out, int out_size, void* d_ws, size_t ws_size,
                              hipStream_t stream) {
    const float* x   = (const float*)d_in[0];
    const float* w1  = (const float*)d_in[1];
    const float* b1g = (const float*)d_in[2];
    const float* b1b = (const float*)d_in[3];
    const float* b1m = (const float*)d_in[4];
    const float* b1v = (const float*)d_in[5];
    const float* r1w = (const float*)d_in[6];
    const float* r1g = (const float*)d_in[7];
    const float* r1b = (const float*)d_in[8];
    const float* r1m = (const float*)d_in[9];
    const float* r1v = (const float*)d_in[10];
    const float* w2  = (const float*)d_in[11];
    const float* b2g = (const float*)d_in[12];
    const float* b2b = (const float*)d_in[13];
    const float* b2m = (const float*)d_in[14];
    const float* b2v = (const float*)d_in[15];
    const float* r2w = (const float*)d_in[16];
    const float* r2g = (const float*)d_in[17];
    const float* r2b = (const float*)d_in[18];
    const float* r2m = (const float*)d_in[19];
    const float* r2v = (const float*)d_in[20];
    const float* w3  = (const float*)d_in[21];
    const float* b3g = (const float*)d_in[22];
    const float* b3b = (const float*)d_in[23];
    const float* b3m = (const float*)d_in[24];
    const float* b3v = (const float*)d_in[25];
    float* out = (float*)d_out;

    char* ws = (char*)d_ws;
    unsigned short* h1c  = (unsigned short*)(ws + 0);            // 77,070,336  bf16 NHWC 56x56
    float*          h2c  = (float*)         (ws + 77070336UL);   // 38,535,168  fp32 NHWC 28x28
    unsigned short* h2b  = (unsigned short*)(ws + 115605504UL);  // 19,267,584  bf16 NHWC 28x28
    unsigned short* wb1  = (unsigned short*)(ws + 134873088UL);  // 42,467,328
    unsigned short* wb2r = (unsigned short*)(ws + 177340416UL);  // 10,616,832
    float*          wt1  = (float*)         (ws + 187957248UL);  //     36,864
    unsigned short* wb2c = (unsigned short*)(ws + 187994112UL);  //    294,912
    unsigned short* wb3c = (unsigned short*)(ws + 188289024UL);  //  1,179,648
    // total 189,468,672 B

    wprep_bf16_k<<<8192, 256, 0, stream>>>(r1w, wb1, (long)64 * 192 * 9 * 192);
    wprep_bf16_k<<<2048, 256, 0, stream>>>(r2w, wb2r, (long)16 * 192 * 9 * 192);
    wprep_tap_k<<<576, 256, 0, stream>>>(w2, wb2c, 192);
    wprep_tap_k<<<2304, 256, 0, stream>>>(w3, wb3c, 768);
    wprep_wt1_k<<<36, 256, 0, stream>>>(w1, wt1);

    conv1_k<<<64 * 56, 192, 0, stream>>>(x, wt1, b1g, b1b, b1m, b1v, h1c);
    region_mfma4_k<0><<<64 * 64, 256, 0, stream>>>(h1c, h1c, wb1, r1g, r1b, r1m, r1v, 8, 56);
    conv2_mfma_k<<<64 * 7, 256, 0, stream>>>(h1c, wb2c, b2g, b2b, b2m, b2v, h2c);
    region_mfma4_k<1><<<16 * 64, 256, 0, stream>>>(h2c, h2b, wb2r, r2g, r2b, r2m, r2v, 4, 28);
    conv3_mfma_k<<<64 * 6, 256, 0, stream>>>(h2b, wb3c, b3g, b3b, b3m, b3v, out);
}

// Round 5
// 876.528 us; speedup vs baseline: 1.2945x; 1.1343x over previous
//
#include <hip/hip_runtime.h>
#include <hip/hip_bf16.h>
#include <math.h>

#define EPSBN 1e-5f

typedef short short8 __attribute__((ext_vector_type(8)));
typedef short short4v __attribute__((ext_vector_type(4)));
typedef float floatx4 __attribute__((ext_vector_type(4)));

__device__ __forceinline__ float gelu_f(float x) {
    return 0.5f * x * (1.0f + erff(x * 0.70710678118654752f));
}

__device__ __forceinline__ unsigned short f2bf(float f) {
    union { float f; unsigned int u; } c; c.f = f;
    unsigned int u = c.u;
    unsigned int r = (u + 0x7FFFu + ((u >> 16) & 1u)) >> 16;   // RNE
    return (unsigned short)r;
}

__device__ __forceinline__ float bf2f(unsigned short h) {
    union { unsigned int u; float f; } c; c.u = ((unsigned int)h) << 16;
    return c.f;
}

// ---------------- weight preps ----------------
// region weights: [G][oc][ic][3][3] fp32 -> [G][oc][t][ic] bf16
__global__ void wprep_bf16_k(const float* __restrict__ w, unsigned short* __restrict__ wb,
                             long total) {
    for (long o = (long)blockIdx.x * blockDim.x + threadIdx.x; o < total;
         o += (long)gridDim.x * blockDim.x) {
        int ic = (int)(o % 192); long t0 = o / 192;
        int t = (int)(t0 % 9); long t1 = t0 / 9;
        int oc = (int)(t1 % 192); long g = t1 / 192;
        wb[o] = f2bf(w[(((size_t)g * 192 + oc) * 192 + ic) * 9 + t]);
    }
}

// downsample weights: [OC][192][2][2] fp32 -> [t4][OC][192] bf16
__global__ void wprep_tap_k(const float* __restrict__ w, unsigned short* __restrict__ wb,
                            int OC) {
    long total = (long)4 * OC * 192;
    for (long o = (long)blockIdx.x * blockDim.x + threadIdx.x; o < total;
         o += (long)gridDim.x * blockDim.x) {
        int ic = (int)(o % 192); long t0 = o / 192;
        int oc = (int)(t0 % OC); int t = (int)(t0 / OC);
        wb[o] = f2bf(w[((size_t)oc * 192 + ic) * 4 + t]);
    }
}

// conv1 weights: [192][48] -> [48][192] fp32
__global__ void wprep_wt1_k(const float* __restrict__ w, float* __restrict__ wt) {
    int o = blockIdx.x * 256 + threadIdx.x;
    if (o < 9216) {
        int oc = o % 192, k = o / 192;
        wt[o] = w[oc * 48 + k];
    }
}

// ---------------- conv1: 3->192, 4x4 stride 4, BN+GELU, NHWC bf16 out ----------------
__global__ __launch_bounds__(192) void conv1_k(
        const float* __restrict__ x, const float* __restrict__ wt1,
        const float* __restrict__ bg, const float* __restrict__ bb,
        const float* __restrict__ bm, const float* __restrict__ bv,
        unsigned short* __restrict__ h1c) {
    __shared__ float xs[3][4][224];
    int b = blockIdx.x / 56, oy = blockIdx.x % 56;
    int tid = threadIdx.x;
    for (int i = tid; i < 2688; i += 192) {
        int col = i % 224, r = (i / 224) % 4, c = i / 896;
        xs[c][r][col] = x[(((size_t)b * 3 + c) * 224 + 4 * oy + r) * 224 + col];
    }
    float w[48];
    #pragma unroll
    for (int k = 0; k < 48; k++) w[k] = wt1[k * 192 + tid];
    float inv = bg[tid] * rsqrtf(bv[tid] + EPSBN);
    float bet = bb[tid] - bm[tid] * inv;
    __syncthreads();
    for (int ox = 0; ox < 56; ox++) {
        float a = 0.f;
        #pragma unroll
        for (int c = 0; c < 3; c++) {
            #pragma unroll
            for (int ky = 0; ky < 4; ky++) {
                float4 v = *(const float4*)&xs[c][ky][4 * ox];
                const float* wk = &w[(c * 4 + ky) * 4];
                a += v.x * wk[0] + v.y * wk[1] + v.z * wk[2] + v.w * wk[3];
            }
        }
        h1c[(((size_t)b * 56 + oy) * 56 + ox) * 192 + tid] = f2bf(gelu_f(a * inv + bet));
    }
}

// ---------------- region conv via MFMA v6: R0 structure + explicit SW pipeline ------------
// Post-mortem R2/R3: every variant sits under all throughput roofs; VGPR_Count=48 (R3)
// shows the compiler issues loads just-in-time -> each of 54 steps exposes ~200-300cy L2
// latency. v6 = R0's proven wave partition (2 tiles, M8xN3, 24 MFMA/step) + explicit
// depth-1 register ping-pong: prefetch step k+1's 3 global + 8 LDS loads into buffer B
// while MFMAing buffer A. Linear address math: lds = cbase[m] + dt(t) + 32*s,
// weight = woff[nt] + 32*step. No dynamic buffer indexing (rule #20).
#define RST 200
#define TILE_SH (81 * RST)
template<int INF32>
__global__ __launch_bounds__(256, 2) void region_mfma3_k(
        const void* __restrict__ inbuf, void* __restrict__ outbuf,
        const unsigned short* __restrict__ wb,
        const float* __restrict__ pg, const float* __restrict__ pb,
        const float* __restrict__ pm, const float* __restrict__ pv,
        int gw, int W) {
    __shared__ unsigned short lds[2 * TILE_SH];   // 64,800 B -> 2 blocks/CU
    const int raw = blockIdx.x;
    const int g = (raw & 7) + 8 * (raw >> 8);
    const int bp = (raw >> 3) & 31;
    const int b0 = bp * 2;
    const int gy = g / gw, gx = g % gw;
    const int Y0 = gy * 7, X0 = gx * 7;
    const int tid = threadIdx.x;
    const int lane = tid & 63;
    const int wid = tid >> 6;
    const int quad = lane >> 4;
    const int l15 = lane & 15;

    const size_t tsz = (size_t)W * W * 192;
    const size_t slab0 = (size_t)b0 * tsz;

    // halo zero (perimeter cells), vectorized
    for (int i = tid; i < 1536; i += 256) {
        int tI = i / 768, rem = i % 768, h = rem / 24, ch = rem % 24;
        int cell;
        if (h < 9) cell = h;
        else if (h < 18) cell = 72 + (h - 9);
        else { int h2 = h - 18; cell = (1 + (h2 >> 1)) * 9 + ((h2 & 1) * 8); }
        *(short8*)&lds[tI * TILE_SH + cell * RST + ch * 8] = (short8)0;
    }
    // interior fill, b128 per lane
    for (int i = tid; i < 2352; i += 256) {
        int tI = i / 1176, rem = i % 1176, p = rem / 24, ch = rem % 24;
        int y = p / 7, xx = p % 7;
        size_t poff = slab0 + (size_t)tI * tsz + ((size_t)(Y0 + y) * W + (X0 + xx)) * 192 + ch * 8;
        short8 v;
        if (INF32) {
            const float* s4 = (const float*)inbuf + poff;
            float4 a = *(const float4*)s4;
            float4 b2 = *(const float4*)(s4 + 4);
            v[0] = (short)f2bf(a.x);  v[1] = (short)f2bf(a.y);
            v[2] = (short)f2bf(a.z);  v[3] = (short)f2bf(a.w);
            v[4] = (short)f2bf(b2.x); v[5] = (short)f2bf(b2.y);
            v[6] = (short)f2bf(b2.z); v[7] = (short)f2bf(b2.w);
        } else {
            v = *(const short8*)((const unsigned short*)inbuf + poff);
        }
        *(short8*)&lds[tI * TILE_SH + ((y + 1) * 9 + (xx + 1)) * RST + ch * 8] = v;
    }
    __syncthreads();

    // per-lane m-frag pixel coords (per tile; same for both tiles)
    int cbase[8];
    #pragma unroll
    for (int f = 0; f < 4; f++) {
        int p = f * 16 + l15; if (p > 48) p = 48;
        int base = ((p / 7) * 9 + (p % 7)) * RST + quad * 8;
        cbase[f] = base;
        cbase[4 + f] = TILE_SH + base;
    }
    // weight offsets: oc = wid*48 + nt*16 + l15
    int woff[3];
    #pragma unroll
    for (int nt = 0; nt < 3; nt++)
        woff[nt] = (wid * 48 + nt * 16 + l15) * 1728 + quad * 8;
    const unsigned short* wbg = wb + (size_t)g * 331776;

    floatx4 acc[8][3];
    #pragma unroll
    for (int m = 0; m < 8; m++)
        #pragma unroll
        for (int nt = 0; nt < 3; nt++) acc[m][nt] = (floatx4)0.f;

    // ---- explicit depth-1 software pipeline over 54 flattened (t,s) steps ----
    short8 wfA[3], pfA[8], wfB[3], pfB[8];
    int sn = 0, kxn = 0, kyn = 0, dtn = 0, soff = 0;

#define ADVANCE() { sn++; if (sn == 6) { sn = 0; kxn++; if (kxn == 3) { kxn = 0; kyn++; } \
                    dtn = (kyn * 9 + kxn) * RST; } soff += 32; }
#define LOADW(WDST) { _Pragma("unroll") for (int nt = 0; nt < 3; nt++) \
                      WDST[nt] = *(const short8*)(wbg + woff[nt] + soff); }
#define LOADP(PDST) { const int o_ = dtn + sn * 32; _Pragma("unroll") for (int m = 0; m < 8; m++) \
                      PDST[m] = *(const short8*)&lds[cbase[m] + o_]; }
#define DOMFMA(PSRC, WSRC) { _Pragma("unroll") for (int m = 0; m < 8; m++) \
                             _Pragma("unroll") for (int nt = 0; nt < 3; nt++) \
                             acc[m][nt] = __builtin_amdgcn_mfma_f32_16x16x32_bf16(PSRC[m], WSRC[nt], acc[m][nt], 0, 0, 0); }

    // prologue: load step 0 into A
    LOADW(wfA); LOADP(pfA);
    #pragma unroll 1
    for (int k = 0; k < 26; k++) {
        ADVANCE(); LOADW(wfB); LOADP(pfB);   // prefetch step 2k+1
        DOMFMA(pfA, wfA);                    // compute step 2k
        ADVANCE(); LOADW(wfA); LOADP(pfA);   // prefetch step 2k+2
        DOMFMA(pfB, wfB);                    // compute step 2k+1
    }
    // tail: steps 52, 53
    ADVANCE(); LOADW(wfB); LOADP(pfB);
    DOMFMA(pfA, wfA);
    DOMFMA(pfB, wfB);

#undef ADVANCE
#undef LOADW
#undef LOADP
#undef DOMFMA

    // epilogue: C row = pixel (f*16 + quad*4 + r), col = oc (l15). Residual from global.
    #pragma unroll
    for (int nt = 0; nt < 3; nt++) {
        int oc = wid * 48 + nt * 16 + l15;
        float inv = pg[g * 192 + oc] * rsqrtf(pv[g * 192 + oc] + EPSBN);
        float bet = pb[g * 192 + oc] - pm[g * 192 + oc] * inv;
        #pragma unroll
        for (int m = 0; m < 8; m++) {
            const int tI = m >> 2;
            const int f = m & 3;
            const size_t tslab = slab0 + (size_t)tI * tsz;
            unsigned short* outb = (unsigned short*)outbuf + tslab;
            const float* resf = (const float*)inbuf + tslab;
            const unsigned short* resu = (const unsigned short*)inbuf + tslab;
            #pragma unroll
            for (int r = 0; r < 4; r++) {
                int p = f * 16 + quad * 4 + r;
                if (p < 49) {
                    int y = p / 7, xx = p % 7;
                    size_t pix = (size_t)(Y0 + y) * W + (X0 + xx);
                    float res = INF32 ? resf[pix * 192 + oc] : bf2f(resu[pix * 192 + oc]);
                    outb[pix * 192 + oc] = f2bf(gelu_f(acc[m][nt][r] * inv + bet) + res);
                }
            }
        }
    }
}

// ---------------- conv2 via MFMA: 192->192, 2x2 s2, BN+GELU, bf16NHWC -> fp32NHWC ----------
__global__ __launch_bounds__(256) void conv2_mfma_k(
        const unsigned short* __restrict__ h1c, const unsigned short* __restrict__ wb,
        const float* __restrict__ bg, const float* __restrict__ bb,
        const float* __restrict__ bm, const float* __restrict__ bv,
        float* __restrict__ h2c) {
    __shared__ unsigned short lds[2 * 112 * 40];
    const int b = blockIdx.x / 7;
    const int oy0 = (blockIdx.x % 7) * 4;
    const int tid = threadIdx.x;
    const int lane = tid & 63;
    const int wid = tid >> 6;
    const int quad = lane >> 4;
    const int l15 = lane & 15;

    floatx4 acc[7][3];
    #pragma unroll
    for (int mt = 0; mt < 7; mt++)
        #pragma unroll
        for (int nt = 0; nt < 3; nt++) acc[mt][nt] = (floatx4)0.f;

    for (int ky = 0; ky < 2; ky++) {
        for (int c = 0; c < 6; c++) {
            __syncthreads();
            for (int i = tid; i < 1792; i += 256) {
                int icq = i & 7, kx = (i >> 3) & 1, p = i >> 4;
                int oy = oy0 + p / 28, ox = p % 28;
                int iy = 2 * oy + ky, ix = 2 * ox + kx;
                const unsigned short* src =
                    h1c + (((size_t)b * 56 + iy) * 56 + ix) * 192 + c * 32 + icq * 4;
                *(short4v*)(&lds[kx * 4480 + p * 40 + icq * 4]) = *(const short4v*)src;
            }
            __syncthreads();
            #pragma unroll
            for (int kx = 0; kx < 2; kx++) {
                const int t = ky * 2 + kx;
                short8 wf[3];
                #pragma unroll
                for (int nt = 0; nt < 3; nt++) {
                    int oc = wid * 48 + nt * 16 + l15;
                    wf[nt] = *(const short8*)(wb + ((size_t)(t * 192 + oc)) * 192 + c * 32 + quad * 8);
                }
                #pragma unroll
                for (int mt = 0; mt < 7; mt++) {
                    short8 ap = *(const short8*)(&lds[kx * 4480 + (mt * 16 + l15) * 40 + quad * 8]);
                    #pragma unroll
                    for (int nt = 0; nt < 3; nt++)
                        acc[mt][nt] = __builtin_amdgcn_mfma_f32_16x16x32_bf16(ap, wf[nt], acc[mt][nt], 0, 0, 0);
                }
            }
        }
    }
    #pragma unroll
    for (int nt = 0; nt < 3; nt++) {
        int oc = wid * 48 + nt * 16 + l15;
        float inv = bg[oc] * rsqrtf(bv[oc] + EPSBN);
        float bet = bb[oc] - bm[oc] * inv;
        #pragma unroll
        for (int mt = 0; mt < 7; mt++) {
            #pragma unroll
            for (int r = 0; r < 4; r++) {
                int p = mt * 16 + quad * 4 + r;
                int oy = oy0 + p / 28, ox = p % 28;
                h2c[(((size_t)b * 28 + oy) * 28 + ox) * 192 + oc] = gelu_f(acc[mt][nt][r] * inv + bet);
            }
        }
    }
}

// ---------------- conv3 via MFMA: 192->768, 2x2 s2, BN, bf16NHWC -> out (B,196,768) ----
__global__ __launch_bounds__(256) void conv3_mfma_k(
        const unsigned short* __restrict__ h2b, const unsigned short* __restrict__ wb,
        const float* __restrict__ bg, const float* __restrict__ bb,
        const float* __restrict__ bm, const float* __restrict__ bv,
        float* __restrict__ out) {
    __shared__ unsigned short lds[2 * 112 * 40];
    const int bid = blockIdx.x;
    const int b = bid / 6;
    const int s = (bid % 6) / 3;
    const int octile = bid % 3;
    const int y0 = s * 7;
    const int tid = threadIdx.x;
    const int lane = tid & 63;
    const int wid = tid >> 6;
    const int quad = lane >> 4;
    const int l15 = lane & 15;

    floatx4 acc[7][4];
    #pragma unroll
    for (int mt = 0; mt < 7; mt++)
        #pragma unroll
        for (int nt = 0; nt < 4; nt++) acc[mt][nt] = (floatx4)0.f;

    for (int ky = 0; ky < 2; ky++) {
        for (int c = 0; c < 6; c++) {
            __syncthreads();
            for (int i = tid; i < 1568; i += 256) {
                int icq = i & 7, kx = (i >> 3) & 1, p = i >> 4;
                int oy = y0 + p / 14, ox = p % 14;
                int iy = 2 * oy + ky, ix = 2 * ox + kx;
                const unsigned short* src =
                    h2b + (((size_t)b * 28 + iy) * 28 + ix) * 192 + c * 32 + icq * 4;
                *(short4v*)(&lds[kx * 4480 + p * 40 + icq * 4]) = *(const short4v*)src;
            }
            __syncthreads();
            #pragma unroll
            for (int kx = 0; kx < 2; kx++) {
                const int t = ky * 2 + kx;
                short8 wf[4];
                #pragma unroll
                for (int nt = 0; nt < 4; nt++) {
                    int oc = octile * 256 + wid * 64 + nt * 16 + l15;
                    wf[nt] = *(const short8*)(wb + ((size_t)(t * 768 + oc)) * 192 + c * 32 + quad * 8);
                }
                #pragma unroll
                for (int mt = 0; mt < 7; mt++) {
                    int p = mt * 16 + l15; if (p > 97) p = 97;
                    short8 ap = *(const short8*)(&lds[kx * 4480 + p * 40 + quad * 8]);
                    #pragma unroll
                    for (int nt = 0; nt < 4; nt++)
                        acc[mt][nt] = __builtin_amdgcn_mfma_f32_16x16x32_bf16(ap, wf[nt], acc[mt][nt], 0, 0, 0);
                }
            }
        }
    }
    #pragma unroll
    for (int nt = 0; nt < 4; nt++) {
        int oc = octile * 256 + wid * 64 + nt * 16 + l15;
        float inv = bg[oc] * rsqrtf(bv[oc] + EPSBN);
        float bet = bb[oc] - bm[oc] * inv;
        #pragma unroll
        for (int mt = 0; mt < 7; mt++) {
            #pragma unroll
            for (int r = 0; r < 4; r++) {
                int p = mt * 16 + quad * 4 + r;
                if (p < 98) {
                    int oy = y0 + p / 14, ox = p % 14;
                    out[((size_t)b * 196 + oy * 14 + ox) * 768 + oc] = acc[mt][nt][r] * inv + bet;
                }
            }
        }
    }
}

extern "C" void kernel_launch(void* const* d_in, const int* in_sizes, int n_in,
                              void* d_out, int out_size, void* d_ws, size_t ws_size,
                              hipStream_t stream) {
    const float* x   = (const float*)d_in[0];
    const float* w1  = (const float*)d_in[1];
    const float* b1g = (const float*)d_in[2];
    const float* b1b = (const float*)d_in[3];
    const float* b1m = (const float*)d_in[4];
    const float* b1v = (const float*)d_in[5];
    const float* r1w = (const float*)d_in[6];
    const float* r1g = (const float*)d_in[7];
    const float* r1b = (const float*)d_in[8];
    const float* r1m = (const float*)d_in[9];
    const float* r1v = (const float*)d_in[10];
    const float* w2  = (const float*)d_in[11];
    const float* b2g = (const float*)d_in[12];
    const float* b2b = (const float*)d_in[13];
    const float* b2m = (const float*)d_in[14];
    const float* b2v = (const float*)d_in[15];
    const float* r2w = (const float*)d_in[16];
    const float* r2g = (const float*)d_in[17];
    const float* r2b = (const float*)d_in[18];
    const float* r2m = (const float*)d_in[19];
    const float* r2v = (const float*)d_in[20];
    const float* w3  = (const float*)d_in[21];
    const float* b3g = (const float*)d_in[22];
    const float* b3b = (const float*)d_in[23];
    const float* b3m = (const float*)d_in[24];
    const float* b3v = (const float*)d_in[25];
    float* out = (float*)d_out;

    char* ws = (char*)d_ws;
    unsigned short* h1c  = (unsigned short*)(ws + 0);            // 77,070,336  bf16 NHWC 56x56
    float*          h2c  = (float*)         (ws + 77070336UL);   // 38,535,168  fp32 NHWC 28x28
    unsigned short* h2b  = (unsigned short*)(ws + 115605504UL);  // 19,267,584  bf16 NHWC 28x28
    unsigned short* wb1  = (unsigned short*)(ws + 134873088UL);  // 42,467,328
    unsigned short* wb2r = (unsigned short*)(ws + 177340416UL);  // 10,616,832
    float*          wt1  = (float*)         (ws + 187957248UL);  //     36,864
    unsigned short* wb2c = (unsigned short*)(ws + 187994112UL);  //    294,912
    unsigned short* wb3c = (unsigned short*)(ws + 188289024UL);  //  1,179,648
    // total 189,468,672 B

    wprep_bf16_k<<<8192, 256, 0, stream>>>(r1w, wb1, (long)64 * 192 * 9 * 192);
    wprep_bf16_k<<<2048, 256, 0, stream>>>(r2w, wb2r, (long)16 * 192 * 9 * 192);
    wprep_tap_k<<<576, 256, 0, stream>>>(w2, wb2c, 192);
    wprep_tap_k<<<2304, 256, 0, stream>>>(w3, wb3c, 768);
    wprep_wt1_k<<<36, 256, 0, stream>>>(w1, wt1);

    conv1_k<<<64 * 56, 192, 0, stream>>>(x, wt1, b1g, b1b, b1m, b1v, h1c);
    region_mfma3_k<0><<<64 * 32, 256, 0, stream>>>(h1c, h1c, wb1, r1g, r1b, r1m, r1v, 8, 56);
    conv2_mfma_k<<<64 * 7, 256, 0, stream>>>(h1c, wb2c, b2g, b2b, b2m, b2v, h2c);
    region_mfma3_k<1><<<16 * 32, 256, 0, stream>>>(h2c, h2b, wb2r, r2g, r2b, r2m, r2v, 4, 28);
    conv3_mfma_k<<<64 * 6, 256, 0, stream>>>(h2b, wb3c, b3g, b3b, b3m, b3v, out);
}